// Round 2
// baseline (408.697 us; speedup 1.0000x reference)
//
#include <hip/hip_runtime.h>
#include <cstddef>

// Problem constants
#define BB 64
#define TT 512
#define DD 1024
#define VV 28

// ---------------------------------------------------------------------------
// K1: hU[t+1][b][v] = x[b,t,:] @ Uo[:,v]   (hU row 0 never read; K3 handles t=0)
//     part[b*16 + tch*2 + half][d] = sum over 32 t-rows of x tile (f32-exact)
// Grid: 512 blocks (b = g>>3, tch = g&7 -> 64 t-rows), 256 threads (4 waves).
// LDS: x tile [64][132] (stride 132: 16B-aligned b128, conflict-free).
// Uo is read directly from global (wave-uniform address -> L1 broadcast),
// keeping the LDS pipe under the FMA budget.
// ---------------------------------------------------------------------------
__global__ __launch_bounds__(256) void k1_hU_rowsum(
    const float* __restrict__ x, const float* __restrict__ Uo,
    float* __restrict__ hU, float* __restrict__ part) {
  __shared__ float xs[64][132];
  const int g   = blockIdx.x;
  const int b   = g >> 3;
  const int tch = g & 7;
  const int t0  = tch << 6;
  const int tid = threadIdx.x;
  const int r2  = tid & 63;   // compute: row within tile (lane == row)
  const int vg  = tid >> 6;   // compute: wave id -> v in [8*vg, 8*vg+8)
  float acc[8];
#pragma unroll
  for (int j = 0; j < 8; ++j) acc[j] = 0.f;
  const float* xbase = x + (size_t)(b * TT + t0) * DD;
  // rowsum assignment: each thread sums 32 rows of one column
  const int rd   = tid & 127;  // local d within chunk
  const int half = tid >> 7;   // row half (0: rows 0-31, 1: rows 32-63)

  for (int c = 0; c < 8; ++c) {
    const int d0 = c << 7;
    __syncthreads();  // previous chunk's reads (compute + rowsum) done
    // stage x tile: 64 rows x 128 cols; consecutive tids -> consecutive
    // float4s within a row (perfect coalescing, 512B per wave instr)
#pragma unroll
    for (int i = 0; i < 8; ++i) {
      const int f   = tid + (i << 8);      // 0..2047
      const int row = f >> 5;
      const int c4  = (f & 31) << 2;
      const float4 vx = *reinterpret_cast<const float4*>(
          xbase + (size_t)row * DD + d0 + c4);
      *reinterpret_cast<float4*>(&xs[row][c4]) = vx;
    }
    __syncthreads();
    // compute: xs per-lane b128 (4 d at a time), Uo rows via uniform global
    const float* up = Uo + (size_t)d0 * VV + (vg << 3);
#pragma unroll 2
    for (int dd = 0; dd < 128; dd += 4) {
      const float4 xv = *reinterpret_cast<const float4*>(&xs[r2][dd]);
      const float xq[4] = {xv.x, xv.y, xv.z, xv.w};
#pragma unroll
      for (int q = 0; q < 4; ++q) {
        const float* ur = up + (size_t)(dd + q) * VV;  // 16B-aligned (28*4=112=7*16)
        const float4 wa = *reinterpret_cast<const float4*>(ur);
        const float4 wb = *reinterpret_cast<const float4*>(ur + 4);
        acc[0] = fmaf(xq[q], wa.x, acc[0]);
        acc[1] = fmaf(xq[q], wa.y, acc[1]);
        acc[2] = fmaf(xq[q], wa.z, acc[2]);
        acc[3] = fmaf(xq[q], wa.w, acc[3]);
        acc[4] = fmaf(xq[q], wb.x, acc[4]);
        acc[5] = fmaf(xq[q], wb.y, acc[5]);
        acc[6] = fmaf(xq[q], wb.z, acc[6]);
        acc[7] = fmaf(xq[q], wb.w, acc[7]);
      }
    }
    // rowsum partials: all 4 waves busy; banks (4r+d)%32, lanes d-consec -> free
    {
      float s = 0.f;
      const int rbase = half << 5;
#pragma unroll 8
      for (int r = 0; r < 32; ++r) s += xs[rbase + r][rd];
      part[(size_t)(b * 16 + tch * 2 + half) * DD + d0 + rd] = s;
    }
  }
  // epilogue: row t feeds step t+1; t = T-1 discarded
  const int t = t0 + r2;
  if (t + 1 < TT) {
    float* o = hU + ((size_t)(t + 1) * BB + b) * VV;
#pragma unroll
    for (int j = 0; j < 8; ++j) {
      const int v = (vg << 3) + j;
      if (v < VV) o[v] = acc[j];
    }
  }
}

// ---------------------------------------------------------------------------
// K2: ctx[b][v] = (sum_t x[b,t,:]) @ Co[:,v];  ew[j] = emb_table[j,:] @ Wo
// Grid: 64 blocks x 256 threads. ctx dot parallelized 8 d-segs x 32 v.
// ---------------------------------------------------------------------------
__global__ __launch_bounds__(256) void k2_ctx_ew(
    const float* __restrict__ part, const float* __restrict__ Co,
    const float* __restrict__ Wo, const float* __restrict__ emb,
    float* __restrict__ ctx, float* __restrict__ ew) {
  __shared__ float rs[DD];
  __shared__ float red[8][32];
  const int b = blockIdx.x;
  const int tid = threadIdx.x;
  for (int d = tid; d < DD; d += 256) {
    float s = 0.f;
#pragma unroll
    for (int k = 0; k < 16; ++k) s += part[(size_t)(b * 16 + k) * DD + d];
    rs[d] = s;
  }
  __syncthreads();
  const int v = tid & 31, seg = tid >> 5;
  float pa = 0.f;
  if (v < VV) {
    const float* cp = Co + (size_t)(seg * 128) * VV + v;
    const float* rp = &rs[seg * 128];
#pragma unroll 4
    for (int d = 0; d < 128; ++d) pa = fmaf(rp[d], cp[(size_t)d * VV], pa);
  }
  red[seg][v] = pa;
  __syncthreads();
  if (tid < 32) {
    float s = 0.f;
#pragma unroll
    for (int k = 0; k < 8; ++k) s += red[k][tid];
    if (tid < VV) ctx[b * VV + tid] = s;
  }
  if (b == 0 && tid >= 64 && tid < 64 + VV) {
    const int j = tid - 64;
    float s = 0.f;
#pragma unroll
    for (int k = 0; k < VV; ++k) s = fmaf(emb[j * VV + k], Wo[k], s);
    ew[j] = s;
  }
}

// ---------------------------------------------------------------------------
// K3: the scan. 1792 independent chains (b,v). Dependent work per step is
// select+compare; both sigmoid candidates depend only on prefetched hU.
// idx = int(sigmoid) is 0 unless sigmoid rounds to exactly 1.0f (z > ~16.63,
// same threshold for exp-form and tanh-form logistic in fp32).
// hU layout [T][B][V] -> gid-contiguous coalesced loads.
// ---------------------------------------------------------------------------
__global__ __launch_bounds__(64) void k3_scan(
    const float* __restrict__ hU, const float* __restrict__ ctx,
    const float* __restrict__ ew, float* __restrict__ out) {
  const int gid = blockIdx.x * 64 + threadIdx.x;  // 0..1791
  const int b = gid / VV;
  const int v = gid - b * VV;
  const float ctxv = ctx[b * VV + v];
  const float e0 = ew[0] + ctxv;
  const float e1 = ew[1] + ctxv;
  const float* hp = hU + (size_t)b * VV + v;
  float* op = out + (size_t)b * TT * VV + v;
  bool s;
  {
    // t = 0: h_prev = 0 and y_prev = 0 -> ew[0], no hU term
    const float y = 1.f / (1.f + expf(-e0));
    s = (y == 1.0f);
    op[0] = y;
  }
#pragma unroll 8
  for (int t = 1; t < TT; ++t) {
    const float h = hp[(size_t)t * (BB * VV)];
    const float c0 = 1.f / (1.f + expf(-(e0 + h)));
    const float c1 = 1.f / (1.f + expf(-(e1 + h)));
    const float y = s ? c1 : c0;
    s = (y == 1.0f);
    op[(size_t)t * VV] = y;
  }
}

// ---------------------------------------------------------------------------
extern "C" void kernel_launch(void* const* d_in, const int* in_sizes, int n_in,
                              void* d_out, int out_size, void* d_ws, size_t ws_size,
                              hipStream_t stream) {
  const float* x   = (const float*)d_in[0];
  // d_in[1]=Wa, d_in[2]=Ua, d_in[3]=Va dead (softmax over size-1 axis == 1)
  const float* Wo  = (const float*)d_in[4];
  const float* Uo  = (const float*)d_in[5];
  const float* Co  = (const float*)d_in[6];
  const float* emb = (const float*)d_in[7];
  float* out = (float*)d_out;

  float* ws   = (float*)d_ws;
  float* hU   = ws;                              // T*B*V    = 917504 f
  float* part = hU + (size_t)TT * BB * VV;       // B*16*D   = 1048576 f
  float* ctx  = part + (size_t)BB * 16 * DD;     // B*V      = 1792 f
  float* ewp  = ctx + BB * VV;                   // 32 f
  // total ~7.9 MB of workspace

  k1_hU_rowsum<<<512, 256, 0, stream>>>(x, Uo, hU, part);
  k2_ctx_ew<<<BB, 256, 0, stream>>>(part, Co, Wo, emb, ctx, ewp);
  k3_scan<<<28, 64, 0, stream>>>(hU, ctx, ewp, out);
}